// Round 3
// baseline (1561.502 us; speedup 1.0000x reference)
//
#include <hip/hip_runtime.h>
#include <hip/hip_bf16.h>

#define NROWS 65536
#define DDIM  2048
#define NEXP  8
#define THREADS 1024
#define NBLOCKS 512
#define ROWS_PER_BLOCK (NROWS / NBLOCKS)        // 128
#define ROWS_PER_WAVE  (ROWS_PER_BLOCK / 16)    // 8
#define PAIRS          (ROWS_PER_WAVE / 2)      // 4
#define KSTEPS         (DDIM / 256)             // 8

// Kernel A: gate scores -> masked softmax -> top1 prob. Writes (p, top1) to
// out[row*8 + {0,1}]; accumulates denom via LDS then 8 global atomics/block.
__global__ __launch_bounds__(THREADS, 8) void gate_kernel(
    const float* __restrict__ x,       // (B, D)
    const int*   __restrict__ label,   // (B,)
    const float* __restrict__ w,       // (D, E) row-major
    const float* __restrict__ bgate,   // (E,)
    float* __restrict__ out,           // (B, E)
    float* __restrict__ denom)         // (E,) pre-zeroed
{
    __shared__ float wt[NEXP * DDIM];  // 64 KiB, wt[e*D + d]
    __shared__ float dsum[NEXP];
    __shared__ float sbg[NEXP];

    const int tid = threadIdx.x;
    if (tid < NEXP) { dsum[tid] = 0.0f; sbg[tid] = bgate[tid]; }

    // Stage w transposed into LDS (coalesced float4 reads, 4 per thread).
    for (int i = tid; i < (DDIM * NEXP) / 4; i += THREADS) {
        float4 v = reinterpret_cast<const float4*>(w)[i];
        const int d0 = i >> 1;
        const int e0 = (i & 1) * 4;
        wt[(e0 + 0) * DDIM + d0] = v.x;
        wt[(e0 + 1) * DDIM + d0] = v.y;
        wt[(e0 + 2) * DDIM + d0] = v.z;
        wt[(e0 + 3) * DDIM + d0] = v.w;
    }
    __syncthreads();

    const int wave = tid >> 6;
    const int lane = tid & 63;
    const int wrow = blockIdx.x * ROWS_PER_BLOCK + wave * ROWS_PER_WAVE;
    const float* xb = x + (size_t)wrow * DDIM + lane * 4;

    for (int p = 0; p < PAIRS; ++p) {
        const int roff0 = (p * 2) * DDIM;
        const int roff1 = (p * 2 + 1) * DDIM;

        float acc[2][NEXP];
#pragma unroll
        for (int e = 0; e < NEXP; ++e) { acc[0][e] = 0.0f; acc[1][e] = 0.0f; }

        // 1-step software pipeline over k.
        float4 cur0 = *reinterpret_cast<const float4*>(xb + roff0);
        float4 cur1 = *reinterpret_cast<const float4*>(xb + roff1);

#pragma unroll
        for (int k = 0; k < KSTEPS; ++k) {
            float4 nxt0, nxt1;
            if (k < KSTEPS - 1) {
                nxt0 = *reinterpret_cast<const float4*>(xb + roff0 + (k + 1) * 256);
                nxt1 = *reinterpret_cast<const float4*>(xb + roff1 + (k + 1) * 256);
            }
#pragma unroll
            for (int e = 0; e < NEXP; ++e) {
                const float4 wv = *reinterpret_cast<const float4*>(&wt[e * DDIM + k * 256 + lane * 4]);
                acc[0][e] += cur0.x * wv.x + cur0.y * wv.y + cur0.z * wv.z + cur0.w * wv.w;
                acc[1][e] += cur1.x * wv.x + cur1.y * wv.y + cur1.z * wv.z + cur1.w * wv.w;
            }
            if (k < KSTEPS - 1) { cur0 = nxt0; cur1 = nxt1; }
        }

        // Per-row: butterfly reduce, then epilogue (keeps live set small).
#pragma unroll
        for (int r = 0; r < 2; ++r) {
            const int row = wrow + p * 2 + r;
            float s[NEXP];
#pragma unroll
            for (int e = 0; e < NEXP; ++e) {
                float v = acc[r][e];
#pragma unroll
                for (int m = 32; m >= 1; m >>= 1)
                    v += __shfl_xor(v, m, 64);
                s[e] = v + sbg[e];
            }

            float mA = s[0]; int aA = 0;
            if (s[1] > mA) { mA = s[1]; aA = 1; }
            if (s[2] > mA) { mA = s[2]; aA = 2; }
            if (s[3] > mA) { mA = s[3]; aA = 3; }
            const float sumA = __expf(s[0] - mA) + __expf(s[1] - mA) +
                               __expf(s[2] - mA) + __expf(s[3] - mA);
            float mB = s[4]; int aB = 4;
            if (s[5] > mB) { mB = s[5]; aB = 5; }
            if (s[6] > mB) { mB = s[6]; aB = 6; }
            if (s[7] > mB) { mB = s[7]; aB = 7; }
            const float sumB = __expf(s[4] - mB) + __expf(s[5] - mB) +
                               __expf(s[6] - mB) + __expf(s[7] - mB);

            const int   lab = label[row];
            const int   arg = lab ? aB : aA;
            const float pv  = 1.0f / (lab ? sumB : sumA);

            if (lane == 0) {
                out[(size_t)row * NEXP + 0] = pv;
                out[(size_t)row * NEXP + 1] = (float)arg;
                atomicAdd(&dsum[arg], pv);
            }
        }
    }

    __syncthreads();
    if (tid < NEXP) atomicAdd(&denom[tid], dsum[tid]);
}

// Kernel B: out[row, e] = (e==top1) ? p/(denom[e]+eps)*B : 0
__global__ __launch_bounds__(256) void finalize_kernel(
    float* __restrict__ out, const float* __restrict__ denom)
{
    const int row = blockIdx.x * blockDim.x + threadIdx.x;
    if (row >= NROWS) return;
    const float p = out[(size_t)row * NEXP + 0];
    const int   a = (int)out[(size_t)row * NEXP + 1];
    const float val = p / (denom[a] + 1e-6f) * 65536.0f;

    float vals[NEXP];
#pragma unroll
    for (int e = 0; e < NEXP; ++e) vals[e] = (e == a) ? val : 0.0f;

    float4* dst = reinterpret_cast<float4*>(out + (size_t)row * NEXP);
    dst[0] = make_float4(vals[0], vals[1], vals[2], vals[3]);
    dst[1] = make_float4(vals[4], vals[5], vals[6], vals[7]);
}

extern "C" void kernel_launch(void* const* d_in, const int* in_sizes, int n_in,
                              void* d_out, int out_size, void* d_ws, size_t ws_size,
                              hipStream_t stream) {
    const float* x     = (const float*)d_in[0];
    const int*   label = (const int*)d_in[1];
    const float* w     = (const float*)d_in[2];
    const float* bg    = (const float*)d_in[3];
    float* out   = (float*)d_out;
    float* denom = (float*)d_ws;   // 8 floats

    hipMemsetAsync(denom, 0, NEXP * sizeof(float), stream);
    gate_kernel<<<NBLOCKS, THREADS, 0, stream>>>(x, label, w, bg, out, denom);
    finalize_kernel<<<NROWS / 256, 256, 0, stream>>>(out, denom);
}

// Round 4
// 1221.226 us; speedup vs baseline: 1.2786x; 1.2786x over previous
//
#include <hip/hip_runtime.h>
#include <hip/hip_bf16.h>

#define NROWS 65536
#define DDIM  2048
#define NEXP  8
#define THREADS 1024
#define NBLOCKS 1024
#define ROWS_PER_BLOCK (NROWS / NBLOCKS)        // 64
#define ROWS_PER_WAVE  (ROWS_PER_BLOCK / 16)    // 4
#define PAIRS          (ROWS_PER_WAVE / 2)      // 2
#define KSTEPS         (DDIM / 256)             // 8

// Kernel A: gate scores -> masked softmax -> top1 prob. Writes (p, top1) to
// out[row*8 + {0,1}]; accumulates denom via LDS then 8 global atomics/block.
// NOTE: no __launch_bounds__ — forcing min-occupancy made the allocator cap
// VGPRs below the ~50-reg live set and spill (R1-R3: WRITE_SIZE 0.65-1.4 GB
// of scratch). Let it allocate naturally; LDS (64 KiB) sets occupancy.
__global__ void gate_kernel(
    const float* __restrict__ x,       // (B, D)
    const int*   __restrict__ label,   // (B,)
    const float* __restrict__ w,       // (D, E) row-major
    const float* __restrict__ bgate,   // (E,)
    float* __restrict__ out,           // (B, E)
    float* __restrict__ denom)         // (E,) pre-zeroed
{
    __shared__ float wt[NEXP * DDIM];  // 64 KiB, wt[e*D + d]
    __shared__ float dsum[NEXP];
    __shared__ float sbg[NEXP];

    const int tid = threadIdx.x;
    if (tid < NEXP) { dsum[tid] = 0.0f; sbg[tid] = bgate[tid]; }

    // Stage w transposed into LDS (coalesced float4 reads).
    for (int i = tid; i < (DDIM * NEXP) / 4; i += THREADS) {
        float4 v = reinterpret_cast<const float4*>(w)[i];
        const int d0 = i >> 1;
        const int e0 = (i & 1) * 4;
        wt[(e0 + 0) * DDIM + d0] = v.x;
        wt[(e0 + 1) * DDIM + d0] = v.y;
        wt[(e0 + 2) * DDIM + d0] = v.z;
        wt[(e0 + 3) * DDIM + d0] = v.w;
    }
    __syncthreads();

    const int wave = tid >> 6;
    const int lane = tid & 63;
    const int wrow = blockIdx.x * ROWS_PER_BLOCK + wave * ROWS_PER_WAVE;
    const float* xb = x + (size_t)wrow * DDIM + lane * 4;

    for (int p = 0; p < PAIRS; ++p) {
        const int roff0 = (p * 2) * DDIM;
        const int roff1 = (p * 2 + 1) * DDIM;

        float acc[2][NEXP];
#pragma unroll
        for (int e = 0; e < NEXP; ++e) { acc[0][e] = 0.0f; acc[1][e] = 0.0f; }

        // 1-step software pipeline over k.
        float4 cur0 = *reinterpret_cast<const float4*>(xb + roff0);
        float4 cur1 = *reinterpret_cast<const float4*>(xb + roff1);

#pragma unroll
        for (int k = 0; k < KSTEPS; ++k) {
            float4 nxt0, nxt1;
            if (k < KSTEPS - 1) {
                nxt0 = *reinterpret_cast<const float4*>(xb + roff0 + (k + 1) * 256);
                nxt1 = *reinterpret_cast<const float4*>(xb + roff1 + (k + 1) * 256);
            }
#pragma unroll
            for (int e = 0; e < NEXP; ++e) {
                const float4 wv = *reinterpret_cast<const float4*>(&wt[e * DDIM + k * 256 + lane * 4]);
                acc[0][e] += cur0.x * wv.x + cur0.y * wv.y + cur0.z * wv.z + cur0.w * wv.w;
                acc[1][e] += cur1.x * wv.x + cur1.y * wv.y + cur1.z * wv.z + cur1.w * wv.w;
            }
            if (k < KSTEPS - 1) { cur0 = nxt0; cur1 = nxt1; }
        }

        // Per-row: butterfly reduce, then epilogue (keeps live set small).
#pragma unroll
        for (int r = 0; r < 2; ++r) {
            const int row = wrow + p * 2 + r;
            float s[NEXP];
#pragma unroll
            for (int e = 0; e < NEXP; ++e) {
                float v = acc[r][e];
#pragma unroll
                for (int m = 32; m >= 1; m >>= 1)
                    v += __shfl_xor(v, m, 64);
                s[e] = v + sbg[e];
            }

            float mA = s[0]; int aA = 0;
            if (s[1] > mA) { mA = s[1]; aA = 1; }
            if (s[2] > mA) { mA = s[2]; aA = 2; }
            if (s[3] > mA) { mA = s[3]; aA = 3; }
            const float sumA = __expf(s[0] - mA) + __expf(s[1] - mA) +
                               __expf(s[2] - mA) + __expf(s[3] - mA);
            float mB = s[4]; int aB = 4;
            if (s[5] > mB) { mB = s[5]; aB = 5; }
            if (s[6] > mB) { mB = s[6]; aB = 6; }
            if (s[7] > mB) { mB = s[7]; aB = 7; }
            const float sumB = __expf(s[4] - mB) + __expf(s[5] - mB) +
                               __expf(s[6] - mB) + __expf(s[7] - mB);

            const int   lab = label[row];
            const int   arg = lab ? aB : aA;
            const float pv  = 1.0f / (lab ? sumB : sumA);

            if (lane == 0) {
                out[(size_t)row * NEXP + 0] = pv;
                out[(size_t)row * NEXP + 1] = (float)arg;
                atomicAdd(&dsum[arg], pv);
            }
        }
    }

    __syncthreads();
    if (tid < NEXP) atomicAdd(&denom[tid], dsum[tid]);
}

// Kernel B: out[row, e] = (e==top1) ? p/(denom[e]+eps)*B : 0
__global__ void finalize_kernel(
    float* __restrict__ out, const float* __restrict__ denom)
{
    const int row = blockIdx.x * blockDim.x + threadIdx.x;
    if (row >= NROWS) return;
    const float p = out[(size_t)row * NEXP + 0];
    const int   a = (int)out[(size_t)row * NEXP + 1];
    const float val = p / (denom[a] + 1e-6f) * 65536.0f;

    float vals[NEXP];
#pragma unroll
    for (int e = 0; e < NEXP; ++e) vals[e] = (e == a) ? val : 0.0f;

    float4* dst = reinterpret_cast<float4*>(out + (size_t)row * NEXP);
    dst[0] = make_float4(vals[0], vals[1], vals[2], vals[3]);
    dst[1] = make_float4(vals[4], vals[5], vals[6], vals[7]);
}

extern "C" void kernel_launch(void* const* d_in, const int* in_sizes, int n_in,
                              void* d_out, int out_size, void* d_ws, size_t ws_size,
                              hipStream_t stream) {
    const float* x     = (const float*)d_in[0];
    const int*   label = (const int*)d_in[1];
    const float* w     = (const float*)d_in[2];
    const float* bg    = (const float*)d_in[3];
    float* out   = (float*)d_out;
    float* denom = (float*)d_ws;   // 8 floats

    hipMemsetAsync(denom, 0, NEXP * sizeof(float), stream);
    gate_kernel<<<NBLOCKS, THREADS, 0, stream>>>(x, label, w, bg, out, denom);
    finalize_kernel<<<NROWS / 256, 256, 0, stream>>>(out, denom);
}

// Round 5
// 445.371 us; speedup vs baseline: 3.5061x; 2.7420x over previous
//
#include <hip/hip_runtime.h>
#include <hip/hip_bf16.h>

#define NROWS 65536
#define DDIM  2048
#define NEXP  8
#define THREADS 512
#define NBLOCKS 1024
#define ROWS_PER_BLOCK (NROWS / NBLOCKS)        // 64
#define ROWS_PER_WAVE  (ROWS_PER_BLOCK / 8)     // 8  (8 waves/block)
#define PAIRS          (ROWS_PER_WAVE / 2)      // 4
#define KSTEPS         (DDIM / 256)             // 8

// Kernel A: gate scores -> masked softmax -> top1 prob. Writes (p, top1) to
// out[row*8 + {0,1}]; accumulates denom via LDS then 8 global atomics/block.
//
// Register-allocation note (R1-R4 evidence): the backend caps VGPRs at the
// occupancy the LDS footprint permits, assuming the declared max block size.
// 1024-thread blocks + 64 KiB LDS -> 8 waves/SIMD -> 64-reg cap -> spills
// (0.85-1.4 GB scratch writes). 512-thread blocks + 64 KiB LDS -> 4
// waves/SIMD -> 128-reg cap, which fits the ~50-reg live set with no spill.
__global__ __launch_bounds__(THREADS) void gate_kernel(
    const float* __restrict__ x,       // (B, D)
    const int*   __restrict__ label,   // (B,)
    const float* __restrict__ w,       // (D, E) row-major
    const float* __restrict__ bgate,   // (E,)
    float* __restrict__ out,           // (B, E)
    float* __restrict__ denom)         // (E,) pre-zeroed
{
    __shared__ float wt[NEXP * DDIM];  // 64 KiB, wt[e*D + d]
    __shared__ float dsum[NEXP];
    __shared__ float sbg[NEXP];

    const int tid = threadIdx.x;
    if (tid < NEXP) { dsum[tid] = 0.0f; sbg[tid] = bgate[tid]; }

    // Stage w transposed into LDS (coalesced float4 reads, 8 per thread).
    for (int i = tid; i < (DDIM * NEXP) / 4; i += THREADS) {
        float4 v = reinterpret_cast<const float4*>(w)[i];
        const int d0 = i >> 1;
        const int e0 = (i & 1) * 4;
        wt[(e0 + 0) * DDIM + d0] = v.x;
        wt[(e0 + 1) * DDIM + d0] = v.y;
        wt[(e0 + 2) * DDIM + d0] = v.z;
        wt[(e0 + 3) * DDIM + d0] = v.w;
    }
    __syncthreads();

    const int wave = tid >> 6;
    const int lane = tid & 63;
    const int wrow = blockIdx.x * ROWS_PER_BLOCK + wave * ROWS_PER_WAVE;
    const float* xb = x + (size_t)wrow * DDIM + lane * 4;

    for (int p = 0; p < PAIRS; ++p) {
        const int roff0 = (p * 2) * DDIM;
        const int roff1 = (p * 2 + 1) * DDIM;

        float acc[2][NEXP];
#pragma unroll
        for (int e = 0; e < NEXP; ++e) { acc[0][e] = 0.0f; acc[1][e] = 0.0f; }

        // 1-step software pipeline over k.
        float4 cur0 = *reinterpret_cast<const float4*>(xb + roff0);
        float4 cur1 = *reinterpret_cast<const float4*>(xb + roff1);

#pragma unroll
        for (int k = 0; k < KSTEPS; ++k) {
            float4 nxt0, nxt1;
            if (k < KSTEPS - 1) {
                nxt0 = *reinterpret_cast<const float4*>(xb + roff0 + (k + 1) * 256);
                nxt1 = *reinterpret_cast<const float4*>(xb + roff1 + (k + 1) * 256);
            }
#pragma unroll
            for (int e = 0; e < NEXP; ++e) {
                const float4 wv = *reinterpret_cast<const float4*>(&wt[e * DDIM + k * 256 + lane * 4]);
                acc[0][e] += cur0.x * wv.x + cur0.y * wv.y + cur0.z * wv.z + cur0.w * wv.w;
                acc[1][e] += cur1.x * wv.x + cur1.y * wv.y + cur1.z * wv.z + cur1.w * wv.w;
            }
            if (k < KSTEPS - 1) { cur0 = nxt0; cur1 = nxt1; }
        }

        // Per-row: butterfly reduce, then epilogue (keeps live set small).
#pragma unroll
        for (int r = 0; r < 2; ++r) {
            const int row = wrow + p * 2 + r;
            float s[NEXP];
#pragma unroll
            for (int e = 0; e < NEXP; ++e) {
                float v = acc[r][e];
#pragma unroll
                for (int m = 32; m >= 1; m >>= 1)
                    v += __shfl_xor(v, m, 64);
                s[e] = v + sbg[e];
            }

            float mA = s[0]; int aA = 0;
            if (s[1] > mA) { mA = s[1]; aA = 1; }
            if (s[2] > mA) { mA = s[2]; aA = 2; }
            if (s[3] > mA) { mA = s[3]; aA = 3; }
            const float sumA = __expf(s[0] - mA) + __expf(s[1] - mA) +
                               __expf(s[2] - mA) + __expf(s[3] - mA);
            float mB = s[4]; int aB = 4;
            if (s[5] > mB) { mB = s[5]; aB = 5; }
            if (s[6] > mB) { mB = s[6]; aB = 6; }
            if (s[7] > mB) { mB = s[7]; aB = 7; }
            const float sumB = __expf(s[4] - mB) + __expf(s[5] - mB) +
                               __expf(s[6] - mB) + __expf(s[7] - mB);

            const int   lab = label[row];
            const int   arg = lab ? aB : aA;
            const float pv  = 1.0f / (lab ? sumB : sumA);

            if (lane == 0) {
                *reinterpret_cast<float2*>(out + (size_t)row * NEXP) =
                    make_float2(pv, (float)arg);
                atomicAdd(&dsum[arg], pv);
            }
        }
    }

    __syncthreads();
    if (tid < NEXP) atomicAdd(&denom[tid], dsum[tid]);
}

// Kernel B: out[row, e] = (e==top1) ? p/(denom[e]+eps)*B : 0
__global__ __launch_bounds__(256) void finalize_kernel(
    float* __restrict__ out, const float* __restrict__ denom)
{
    const int row = blockIdx.x * blockDim.x + threadIdx.x;
    if (row >= NROWS) return;
    const float p = out[(size_t)row * NEXP + 0];
    const int   a = (int)out[(size_t)row * NEXP + 1];
    const float val = p / (denom[a] + 1e-6f) * 65536.0f;

    float vals[NEXP];
#pragma unroll
    for (int e = 0; e < NEXP; ++e) vals[e] = (e == a) ? val : 0.0f;

    float4* dst = reinterpret_cast<float4*>(out + (size_t)row * NEXP);
    dst[0] = make_float4(vals[0], vals[1], vals[2], vals[3]);
    dst[1] = make_float4(vals[4], vals[5], vals[6], vals[7]);
}

extern "C" void kernel_launch(void* const* d_in, const int* in_sizes, int n_in,
                              void* d_out, int out_size, void* d_ws, size_t ws_size,
                              hipStream_t stream) {
    const float* x     = (const float*)d_in[0];
    const int*   label = (const int*)d_in[1];
    const float* w     = (const float*)d_in[2];
    const float* bg    = (const float*)d_in[3];
    float* out   = (float*)d_out;
    float* denom = (float*)d_ws;   // 8 floats

    hipMemsetAsync(denom, 0, NEXP * sizeof(float), stream);
    gate_kernel<<<NBLOCKS, THREADS, 0, stream>>>(x, label, w, bg, out, denom);
    finalize_kernel<<<NROWS / 256, 256, 0, stream>>>(out, denom);
}

// Round 6
// 125.679 us; speedup vs baseline: 12.4246x; 3.5437x over previous
//
#include <hip/hip_runtime.h>
#include <hip/hip_bf16.h>

#define NROWS 65536
#define DDIM  2048
#define NEXP  8
#define THREADS 512
#define NBLOCKS 1024
#define ROWS_PER_BLOCK (NROWS / NBLOCKS)        // 64
#define ROWS_PER_WAVE  (ROWS_PER_BLOCK / 8)     // 8  (8 waves/block)
#define PAIRS          (ROWS_PER_WAVE / 2)      // 4
#define KSTEPS         (DDIM / 256)             // 8

// Kernel A: gate scores -> masked softmax -> top1 prob. Writes (p, top1) to
// out[row*8 + {0,1}]; accumulates denom via LDS then 8 global atomics/block.
//
// R1-R5 lessons baked in:
//  - 512-thr blocks + 64 KiB LDS -> allocator caps at 128 VGPRs (2 blk/CU,
//    4 waves/SIMD). 1024-thr blocks cap at 64 -> spill. Keep 512.
//  - NO explicit software pipeline: cur/nxt double-buffer forced 32 live regs
//    and full-unroll hoisting pushed demand past 128 -> 200 MB scratch (R5).
//    15 sibling waves cover the ~900cy HBM latency (need ~7). unroll 4 bounds
//    the compiler's own hoisting.
__global__ __launch_bounds__(THREADS) void gate_kernel(
    const float* __restrict__ x,       // (B, D)
    const int*   __restrict__ label,   // (B,)
    const float* __restrict__ w,       // (D, E) row-major
    const float* __restrict__ bgate,   // (E,)
    float* __restrict__ out,           // (B, E)
    float* __restrict__ denom)         // (E,) pre-zeroed
{
    __shared__ float wt[NEXP * DDIM];  // 64 KiB, wt[e*D + d]
    __shared__ float dsum[NEXP];
    __shared__ float sbg[NEXP];

    const int tid = threadIdx.x;
    if (tid < NEXP) { dsum[tid] = 0.0f; sbg[tid] = bgate[tid]; }

    // Stage w transposed into LDS (coalesced float4 reads, 8 per thread).
    for (int i = tid; i < (DDIM * NEXP) / 4; i += THREADS) {
        float4 v = reinterpret_cast<const float4*>(w)[i];
        const int d0 = i >> 1;
        const int e0 = (i & 1) * 4;
        wt[(e0 + 0) * DDIM + d0] = v.x;
        wt[(e0 + 1) * DDIM + d0] = v.y;
        wt[(e0 + 2) * DDIM + d0] = v.z;
        wt[(e0 + 3) * DDIM + d0] = v.w;
    }
    __syncthreads();

    const int wave = tid >> 6;
    const int lane = tid & 63;
    const int wrow = blockIdx.x * ROWS_PER_BLOCK + wave * ROWS_PER_WAVE;
    const float* xb = x + (size_t)wrow * DDIM + lane * 4;

    for (int p = 0; p < PAIRS; ++p) {
        const int roff0 = (p * 2) * DDIM;
        const int roff1 = roff0 + DDIM;

        float acc0[NEXP], acc1[NEXP];
#pragma unroll
        for (int e = 0; e < NEXP; ++e) { acc0[e] = 0.0f; acc1[e] = 0.0f; }

#pragma unroll 4
        for (int k = 0; k < KSTEPS; ++k) {
            const float4 a = *reinterpret_cast<const float4*>(xb + roff0 + k * 256);
            const float4 b = *reinterpret_cast<const float4*>(xb + roff1 + k * 256);
#pragma unroll
            for (int e = 0; e < NEXP; ++e) {
                const float4 wv = *reinterpret_cast<const float4*>(&wt[e * DDIM + k * 256 + lane * 4]);
                acc0[e] += a.x * wv.x + a.y * wv.y + a.z * wv.z + a.w * wv.w;
                acc1[e] += b.x * wv.x + b.y * wv.y + b.z * wv.z + b.w * wv.w;
            }
        }

        // Per-row: butterfly reduce, then epilogue (keeps live set small).
#pragma unroll
        for (int r = 0; r < 2; ++r) {
            const int row = wrow + p * 2 + r;
            float s[NEXP];
#pragma unroll
            for (int e = 0; e < NEXP; ++e) {
                float v = r ? acc1[e] : acc0[e];
#pragma unroll
                for (int m = 32; m >= 1; m >>= 1)
                    v += __shfl_xor(v, m, 64);
                s[e] = v + sbg[e];
            }

            float mA = s[0]; int aA = 0;
            if (s[1] > mA) { mA = s[1]; aA = 1; }
            if (s[2] > mA) { mA = s[2]; aA = 2; }
            if (s[3] > mA) { mA = s[3]; aA = 3; }
            const float sumA = __expf(s[0] - mA) + __expf(s[1] - mA) +
                               __expf(s[2] - mA) + __expf(s[3] - mA);
            float mB = s[4]; int aB = 4;
            if (s[5] > mB) { mB = s[5]; aB = 5; }
            if (s[6] > mB) { mB = s[6]; aB = 6; }
            if (s[7] > mB) { mB = s[7]; aB = 7; }
            const float sumB = __expf(s[4] - mB) + __expf(s[5] - mB) +
                               __expf(s[6] - mB) + __expf(s[7] - mB);

            const int   lab = label[row];
            const int   arg = lab ? aB : aA;
            const float pv  = 1.0f / (lab ? sumB : sumA);

            if (lane == 0) {
                *reinterpret_cast<float2*>(out + (size_t)row * NEXP) =
                    make_float2(pv, (float)arg);
                atomicAdd(&dsum[arg], pv);
            }
        }
    }

    __syncthreads();
    if (tid < NEXP) atomicAdd(&denom[tid], dsum[tid]);
}

// Kernel B: out[row, e] = (e==top1) ? p/(denom[e]+eps)*B : 0
__global__ __launch_bounds__(256) void finalize_kernel(
    float* __restrict__ out, const float* __restrict__ denom)
{
    const int row = blockIdx.x * blockDim.x + threadIdx.x;
    if (row >= NROWS) return;
    const float p = out[(size_t)row * NEXP + 0];
    const int   a = (int)out[(size_t)row * NEXP + 1];
    const float val = p / (denom[a] + 1e-6f) * 65536.0f;

    float vals[NEXP];
#pragma unroll
    for (int e = 0; e < NEXP; ++e) vals[e] = (e == a) ? val : 0.0f;

    float4* dst = reinterpret_cast<float4*>(out + (size_t)row * NEXP);
    dst[0] = make_float4(vals[0], vals[1], vals[2], vals[3]);
    dst[1] = make_float4(vals[4], vals[5], vals[6], vals[7]);
}

extern "C" void kernel_launch(void* const* d_in, const int* in_sizes, int n_in,
                              void* d_out, int out_size, void* d_ws, size_t ws_size,
                              hipStream_t stream) {
    const float* x     = (const float*)d_in[0];
    const int*   label = (const int*)d_in[1];
    const float* w     = (const float*)d_in[2];
    const float* bg    = (const float*)d_in[3];
    float* out   = (float*)d_out;
    float* denom = (float*)d_ws;   // 8 floats

    hipMemsetAsync(denom, 0, NEXP * sizeof(float), stream);
    gate_kernel<<<NBLOCKS, THREADS, 0, stream>>>(x, label, w, bg, out, denom);
    finalize_kernel<<<NROWS / 256, 256, 0, stream>>>(out, denom);
}

// Round 8
// 118.885 us; speedup vs baseline: 13.1346x; 1.0571x over previous
//
#include <hip/hip_runtime.h>
#include <hip/hip_bf16.h>

#define NROWS 65536
#define DDIM  2048
#define NEXP  8
#define THREADS 512
#define NBLOCKS 512
#define ROWS_PER_BLOCK (NROWS / NBLOCKS)        // 128
#define ROWS_PER_WAVE  (ROWS_PER_BLOCK / 8)     // 16 (8 waves/block)
#define PAIRS          (ROWS_PER_WAVE / 2)      // 8
#define KSTEPS         (DDIM / 256)             // 8

typedef float v4f __attribute__((ext_vector_type(4)));
typedef float v2f __attribute__((ext_vector_type(2)));

// Kernel A: gate scores -> masked softmax -> top1 prob. Writes (p, top1) to
// out[row*8 + {0,1}]; accumulates denom via LDS then 8 global atomics/block.
//
// R1-R7 lessons baked in:
//  - 512-thr blocks + 64 KiB LDS -> allocator caps at 128 VGPRs (2 blk/CU,
//    4 waves/SIMD); fits the ~70-reg live set. 1024-thr blocks -> 64-reg
//    cap -> spill (R2-R4). Explicit cur/nxt double-buffer -> 200 MB scratch
//    (R5). Keep: natural loads, unroll 4, 512 threads.
//  - 512 blocks: single generation, w staged once per CU-slot.
//  - Non-temporal x loads (stream-once; don't evict w/out from L2/LLC).
//    NOTE: nontemporal builtins need native clang vector types (ext_vector),
//    not HIP_vector_type (R7 compile error).
__global__ __launch_bounds__(THREADS) void gate_kernel(
    const float* __restrict__ x,       // (B, D)
    const int*   __restrict__ label,   // (B,)
    const float* __restrict__ w,       // (D, E) row-major
    const float* __restrict__ bgate,   // (E,)
    float* __restrict__ out,           // (B, E)
    float* __restrict__ denom)         // (E,) pre-zeroed
{
    __shared__ float wt[NEXP * DDIM];  // 64 KiB, wt[e*D + d]
    __shared__ float dsum[NEXP];
    __shared__ float sbg[NEXP];

    const int tid = threadIdx.x;
    if (tid < NEXP) { dsum[tid] = 0.0f; sbg[tid] = bgate[tid]; }

    // Stage w transposed into LDS (coalesced float4 reads, 8 per thread).
    for (int i = tid; i < (DDIM * NEXP) / 4; i += THREADS) {
        v4f v = *reinterpret_cast<const v4f*>(w + 4 * (size_t)i);
        const int d0 = i >> 1;
        const int e0 = (i & 1) * 4;
        wt[(e0 + 0) * DDIM + d0] = v.x;
        wt[(e0 + 1) * DDIM + d0] = v.y;
        wt[(e0 + 2) * DDIM + d0] = v.z;
        wt[(e0 + 3) * DDIM + d0] = v.w;
    }
    __syncthreads();

    const int wave = tid >> 6;
    const int lane = tid & 63;
    const int wrow = blockIdx.x * ROWS_PER_BLOCK + wave * ROWS_PER_WAVE;
    const float* xb = x + (size_t)wrow * DDIM + lane * 4;

    for (int p = 0; p < PAIRS; ++p) {
        const int roff0 = (p * 2) * DDIM;
        const int roff1 = roff0 + DDIM;

        float acc0[NEXP], acc1[NEXP];
#pragma unroll
        for (int e = 0; e < NEXP; ++e) { acc0[e] = 0.0f; acc1[e] = 0.0f; }

#pragma unroll 4
        for (int k = 0; k < KSTEPS; ++k) {
            const v4f a = __builtin_nontemporal_load(
                reinterpret_cast<const v4f*>(xb + roff0 + k * 256));
            const v4f b = __builtin_nontemporal_load(
                reinterpret_cast<const v4f*>(xb + roff1 + k * 256));
#pragma unroll
            for (int e = 0; e < NEXP; ++e) {
                const v4f wv = *reinterpret_cast<const v4f*>(&wt[e * DDIM + k * 256 + lane * 4]);
                acc0[e] += a.x * wv.x + a.y * wv.y + a.z * wv.z + a.w * wv.w;
                acc1[e] += b.x * wv.x + b.y * wv.y + b.z * wv.z + b.w * wv.w;
            }
        }

        // Per-row: butterfly reduce, then epilogue (keeps live set small).
#pragma unroll
        for (int r = 0; r < 2; ++r) {
            const int row = wrow + p * 2 + r;
            float s[NEXP];
#pragma unroll
            for (int e = 0; e < NEXP; ++e) {
                float v = r ? acc1[e] : acc0[e];
#pragma unroll
                for (int m = 32; m >= 1; m >>= 1)
                    v += __shfl_xor(v, m, 64);
                s[e] = v + sbg[e];
            }

            float mA = s[0]; int aA = 0;
            if (s[1] > mA) { mA = s[1]; aA = 1; }
            if (s[2] > mA) { mA = s[2]; aA = 2; }
            if (s[3] > mA) { mA = s[3]; aA = 3; }
            const float sumA = __expf(s[0] - mA) + __expf(s[1] - mA) +
                               __expf(s[2] - mA) + __expf(s[3] - mA);
            float mB = s[4]; int aB = 4;
            if (s[5] > mB) { mB = s[5]; aB = 5; }
            if (s[6] > mB) { mB = s[6]; aB = 6; }
            if (s[7] > mB) { mB = s[7]; aB = 7; }
            const float sumB = __expf(s[4] - mB) + __expf(s[5] - mB) +
                               __expf(s[6] - mB) + __expf(s[7] - mB);

            const int   lab = label[row];
            const int   arg = lab ? aB : aA;
            const float pv  = 1.0f / (lab ? sumB : sumA);

            if (lane == 0) {
                v2f o; o.x = pv; o.y = (float)arg;
                __builtin_nontemporal_store(
                    o, reinterpret_cast<v2f*>(out + (size_t)row * NEXP));
                atomicAdd(&dsum[arg], pv);
            }
        }
    }

    __syncthreads();
    if (tid < NEXP) atomicAdd(&denom[tid], dsum[tid]);
}

// Kernel B: out[row, e] = (e==top1) ? p/(denom[e]+eps)*B : 0
__global__ __launch_bounds__(256) void finalize_kernel(
    float* __restrict__ out, const float* __restrict__ denom)
{
    const int row = blockIdx.x * blockDim.x + threadIdx.x;
    if (row >= NROWS) return;
    const float p = out[(size_t)row * NEXP + 0];
    const int   a = (int)out[(size_t)row * NEXP + 1];
    const float val = p / (denom[a] + 1e-6f) * 65536.0f;

    float vals[NEXP];
#pragma unroll
    for (int e = 0; e < NEXP; ++e) vals[e] = (e == a) ? val : 0.0f;

    v4f o0; o0.x = vals[0]; o0.y = vals[1]; o0.z = vals[2]; o0.w = vals[3];
    v4f o1; o1.x = vals[4]; o1.y = vals[5]; o1.z = vals[6]; o1.w = vals[7];
    v4f* dst = reinterpret_cast<v4f*>(out + (size_t)row * NEXP);
    __builtin_nontemporal_store(o0, dst);
    __builtin_nontemporal_store(o1, dst + 1);
}

extern "C" void kernel_launch(void* const* d_in, const int* in_sizes, int n_in,
                              void* d_out, int out_size, void* d_ws, size_t ws_size,
                              hipStream_t stream) {
    const float* x     = (const float*)d_in[0];
    const int*   label = (const int*)d_in[1];
    const float* w     = (const float*)d_in[2];
    const float* bg    = (const float*)d_in[3];
    float* out   = (float*)d_out;
    float* denom = (float*)d_ws;   // 8 floats

    (void)hipMemsetAsync(denom, 0, NEXP * sizeof(float), stream);
    gate_kernel<<<NBLOCKS, THREADS, 0, stream>>>(x, label, w, bg, out, denom);
    finalize_kernel<<<NROWS / 256, 256, 0, stream>>>(out, denom);
}